// Round 1
// baseline (107.356 us; speedup 1.0000x reference)
//
#include <hip/hip_runtime.h>
#include <hip/hip_bf16.h>
#include <stdint.h>

#define B_ 2
#define S_ 2048
#define E_ 512
#define H_ 8
#define DH_ 64
#define BH_ (B_*H_)
#define M_ (B_*S_)  // 4096

typedef short short8 __attribute__((ext_vector_type(8)));
typedef float f32x4 __attribute__((ext_vector_type(4)));

__device__ __forceinline__ ushort f2bf(float f) {
  uint32_t u = __builtin_bit_cast(uint32_t, f);
  u += 0x7fffu + ((u >> 16) & 1u);
  return (ushort)(u >> 16);
}

__device__ __forceinline__ void gll16(const void* g, void* l) {
  __builtin_amdgcn_global_load_lds((const __attribute__((address_space(1))) void*)g,
                                   (__attribute__((address_space(3))) void*)l,
                                   16, 0, 0);
}

// ---------------- fp32 -> bf16 conversion ----------------
struct CvtArgs {
  const float* s[7];
  ushort* d[7];
  int nq[7];
};

__global__ __launch_bounds__(256) void cvt_kernel(CvtArgs a) {
  int seg = blockIdx.y;
  int i = blockIdx.x * 256 + threadIdx.x;
  if (i >= a.nq[seg]) return;
  float4 v = ((const float4*)a.s[seg])[i];
  ushort4 o;
  o.x = f2bf(v.x); o.y = f2bf(v.y); o.z = f2bf(v.z); o.w = f2bf(v.w);
  ((ushort4*)a.d[seg])[i] = o;
}

// ---------------- bf16 GEMM: out = A @ W^T + bias ----------------
// A [M,K] row-major bf16, W [N,K] row-major bf16 (nn.Linear weight).
// EPI 0: bf16 out, head-separated [BH][S][DH], scale applied (0.125 for z==0)
// EPI 1: fp32 out, [M][N] linear
template<int EPI>
__global__ __launch_bounds__(256) void gemm_bt(
    const ushort* __restrict__ A0, const ushort* __restrict__ A1, const ushort* __restrict__ A2,
    const ushort* __restrict__ W0, const ushort* __restrict__ W1, const ushort* __restrict__ W2,
    const float* __restrict__ bias0, const float* __restrict__ bias1, const float* __restrict__ bias2,
    ushort* O0, ushort* O1, ushort* O2, float* Yout)
{
  const int K = E_;
  int z = blockIdx.z;
  const ushort* A = (z == 0) ? A0 : ((z == 1) ? A1 : A2);
  const ushort* W = (z == 0) ? W0 : ((z == 1) ? W1 : W2);
  const float* bias = (z == 0) ? bias0 : ((z == 1) ? bias1 : bias2);
  ushort* O = (z == 0) ? O0 : ((z == 1) ? O1 : O2);
  float scale = (EPI == 0 && z == 0) ? 0.125f : 1.0f;

  int n0 = blockIdx.x * 128, m0 = blockIdx.y * 128;
  int tid = threadIdx.x, lane = tid & 63, wid = tid >> 6;
  int wm = wid >> 1, wn = wid & 1;

  __shared__ ushort As[128 * 32];
  __shared__ ushort Bs[128 * 32];

  f32x4 acc[4][4];
#pragma unroll
  for (int i = 0; i < 4; ++i)
#pragma unroll
    for (int j = 0; j < 4; ++j)
      acc[i][j] = (f32x4){0.f, 0.f, 0.f, 0.f};

  for (int kt = 0; kt < K / 32; ++kt) {
    int k0 = kt * 32;
    // stage A tile [128][32] and B tile [128][32]; rows are 64B = 4 chunks.
    // LDS dest linear; global source inverse-swizzled: chunk c stores logical c^((r>>1)&3)
#pragma unroll
    for (int c = 0; c < 2; ++c) {
      int f = c * 256 + tid;
      int r = f >> 2;
      int lc = (f & 3) ^ ((r >> 1) & 3);
      gll16(A + (m0 + r) * K + k0 + lc * 8, (char*)As + (c * 256 + wid * 64) * 16);
    }
#pragma unroll
    for (int c = 0; c < 2; ++c) {
      int f = c * 256 + tid;
      int r = f >> 2;
      int lc = (f & 3) ^ ((r >> 1) & 3);
      gll16(W + (n0 + r) * K + k0 + lc * 8, (char*)Bs + (c * 256 + wid * 64) * 16);
    }
    __syncthreads();

    short8 af[4], bf[4];
#pragma unroll
    for (int fm = 0; fm < 4; ++fm) {
      int r = wm * 64 + fm * 16 + (lane & 15);
      int phys = (lane >> 4) ^ ((r >> 1) & 3);
      af[fm] = *(const short8*)((const char*)As + r * 64 + phys * 16);
    }
#pragma unroll
    for (int fn = 0; fn < 4; ++fn) {
      int r = wn * 64 + fn * 16 + (lane & 15);
      int phys = (lane >> 4) ^ ((r >> 1) & 3);
      bf[fn] = *(const short8*)((const char*)Bs + r * 64 + phys * 16);
    }
#pragma unroll
    for (int fm = 0; fm < 4; ++fm)
#pragma unroll
      for (int fn = 0; fn < 4; ++fn)
        acc[fm][fn] = __builtin_amdgcn_mfma_f32_16x16x32_bf16(af[fm], bf[fn], acc[fm][fn], 0, 0, 0);
    __syncthreads();
  }

#pragma unroll
  for (int fm = 0; fm < 4; ++fm) {
#pragma unroll
    for (int fn = 0; fn < 4; ++fn) {
#pragma unroll
      for (int j = 0; j < 4; ++j) {
        int m = m0 + wm * 64 + fm * 16 + (lane >> 4) * 4 + j;
        int n = n0 + wn * 64 + fn * 16 + (lane & 15);
        float v = (acc[fm][fn][j] + bias[n]) * scale;
        if constexpr (EPI == 0) {
          int b = m >> 11, s = m & (S_ - 1);
          int h = n >> 6, d = n & 63;
          O[((b * H_ + h) * S_ + s) * DH_ + d] = f2bf(v);
        } else {
          Yout[m * E_ + n] = v;
        }
      }
    }
  }
}

// ---------------- V transpose: [BH][S][DH] -> [BH][DH][S] ----------------
__global__ __launch_bounds__(256) void vtrans(const ushort* __restrict__ Vh, ushort* __restrict__ Vt) {
  int bh = blockIdx.y;
  int s0 = blockIdx.x * 64;
  __shared__ ushort t[64][72];
  int tid = threadIdx.x;
  const ushort* src = Vh + ((size_t)bh * S_ + s0) * DH_;
  int r = tid >> 2, c0 = (tid & 3) * 16;
#pragma unroll
  for (int i = 0; i < 2; ++i) {
    short8 v = *(const short8*)(src + r * DH_ + c0 + i * 8);
#pragma unroll
    for (int kx = 0; kx < 8; ++kx) t[r][c0 + i * 8 + kx] = (ushort)v[kx];
  }
  __syncthreads();
  int d = tid >> 2, j0 = (tid & 3) * 16;
  ushort* dst = Vt + ((size_t)bh * DH_ + d) * S_ + s0 + j0;
#pragma unroll
  for (int i = 0; i < 2; ++i) {
    short8 o;
#pragma unroll
    for (int kx = 0; kx < 8; ++kx) o[kx] = (short)t[j0 + i * 8 + kx][d];
    *(short8*)(dst + i * 8) = o;
  }
}

// ---------------- flash attention ----------------
// Q [BH][S][64] bf16 (pre-scaled by 0.125), K [BH][S][64] bf16, Vt [BH][64][S] bf16.
// Block: 64 q-rows (4 waves x 16), KV tiles of 128. Out X [B][S][E] bf16.
__global__ __launch_bounds__(256) void attn_kernel(const ushort* __restrict__ Qh,
                                                   const ushort* __restrict__ Kh,
                                                   const ushort* __restrict__ Vt,
                                                   ushort* __restrict__ X) {
  int qt = blockIdx.x, bh = blockIdx.y;
  int q0 = qt * 64;
  int tid = threadIdx.x, lane = tid & 63, wid = tid >> 6;

  __shared__ ushort Qs[64 * 64];   // rows 128B, 8 chunks, swizzled ^ (q&7)
  __shared__ ushort Ks[128 * 64];  // rows 128B, 8 chunks, swizzled ^ (kr&7)
  __shared__ ushort Vs[64 * 128];  // rows 256B, 16 chunks, swizzled ^ (d&7)
  __shared__ ushort Ps[4 * 16 * 128]; // per-wave 16x128, rows 256B, swizzled ^ (r&7)

  const ushort* Qg = Qh + ((size_t)bh * S_ + q0) * DH_;
  const ushort* Kg = Kh + (size_t)bh * S_ * DH_;
  const ushort* Vg = Vt + (size_t)bh * DH_ * S_;

  // stage Q once (512 x 16B)
#pragma unroll
  for (int c = 0; c < 2; ++c) {
    int f = c * 256 + tid;
    int r = f >> 3;
    int lc = (f & 7) ^ (r & 7);
    gll16(Qg + r * DH_ + lc * 8, (char*)Qs + (c * 256 + wid * 64) * 16);
  }

  float m_r[4], l_r[4];
  f32x4 accO[4];
#pragma unroll
  for (int j = 0; j < 4; ++j) { m_r[j] = -INFINITY; l_r[j] = 0.f; }
#pragma unroll
  for (int fo = 0; fo < 4; ++fo) accO[fo] = (f32x4){0.f, 0.f, 0.f, 0.f};

  char* Pw = (char*)Ps + wid * 4096;

  for (int kt = 0; kt < S_ / 128; ++kt) {
    // stage K tile [128][64] and V tile [64][128]
#pragma unroll
    for (int c = 0; c < 4; ++c) {
      int f = c * 256 + tid;
      int r = f >> 3;
      int lc = (f & 7) ^ (r & 7);
      gll16(Kg + (kt * 128 + r) * DH_ + lc * 8, (char*)Ks + (c * 256 + wid * 64) * 16);
    }
#pragma unroll
    for (int c = 0; c < 4; ++c) {
      int f = c * 256 + tid;
      int d = f >> 4;
      int lc = (f & 15) ^ (d & 7);
      gll16(Vg + d * S_ + kt * 128 + lc * 8, (char*)Vs + (c * 256 + wid * 64) * 16);
    }
    __syncthreads();

    // QK^T: 16 q-rows x 128 k-cols per wave
    short8 aq[2];
#pragma unroll
    for (int kd = 0; kd < 2; ++kd) {
      int q = wid * 16 + (lane & 15);
      int phys = (kd * 4 + (lane >> 4)) ^ (q & 7);
      aq[kd] = *(const short8*)((const char*)Qs + q * 128 + phys * 16);
    }
    f32x4 sa[8];
#pragma unroll
    for (int fn = 0; fn < 8; ++fn) {
      sa[fn] = (f32x4){0.f, 0.f, 0.f, 0.f};
#pragma unroll
      for (int kd = 0; kd < 2; ++kd) {
        int kr = fn * 16 + (lane & 15);
        int phys = (kd * 4 + (lane >> 4)) ^ (kr & 7);
        short8 bk = *(const short8*)((const char*)Ks + kr * 128 + phys * 16);
        sa[fn] = __builtin_amdgcn_mfma_f32_16x16x32_bf16(aq[kd], bk, sa[fn], 0, 0, 0);
      }
    }

    // online softmax: row r=(lane>>4)*4+j lives in lanes of this quarter; cols spread over 16 lanes
#pragma unroll
    for (int j = 0; j < 4; ++j) {
      float mx = sa[0][j];
#pragma unroll
      for (int fn = 1; fn < 8; ++fn) mx = fmaxf(mx, sa[fn][j]);
#pragma unroll
      for (int msk = 1; msk < 16; msk <<= 1) mx = fmaxf(mx, __shfl_xor(mx, msk));
      float mnew = fmaxf(m_r[j], mx);
      float sc = __expf(m_r[j] - mnew);
      m_r[j] = mnew;
      float rs = 0.f;
#pragma unroll
      for (int fn = 0; fn < 8; ++fn) {
        float p = __expf(sa[fn][j] - mnew);
        sa[fn][j] = p;
        rs += p;
      }
#pragma unroll
      for (int msk = 1; msk < 16; msk <<= 1) rs += __shfl_xor(rs, msk);
      l_r[j] = l_r[j] * sc + rs;
#pragma unroll
      for (int fo = 0; fo < 4; ++fo) accO[fo][j] *= sc;
    }

    // write P (bf16) to per-wave LDS, swizzled
#pragma unroll
    for (int fn = 0; fn < 8; ++fn) {
#pragma unroll
      for (int j = 0; j < 4; ++j) {
        int rr = (lane >> 4) * 4 + j;
        int cc = fn * 16 + (lane & 15);
        int phys = (cc >> 3) ^ (rr & 7);
        *(ushort*)(Pw + rr * 256 + phys * 16 + (cc & 7) * 2) = f2bf(sa[fn][j]);
      }
    }
    __syncthreads();

    // PV: O += P[16x128] @ V[128x64]
#pragma unroll
    for (int ks = 0; ks < 4; ++ks) {
      int rp = lane & 15;
      int physp = (ks * 4 + (lane >> 4)) ^ (rp & 7);
      short8 ap = *(const short8*)((const char*)Pw + rp * 256 + physp * 16);
#pragma unroll
      for (int fo = 0; fo < 4; ++fo) {
        int d = fo * 16 + (lane & 15);
        int physv = (ks * 4 + (lane >> 4)) ^ (d & 7);
        short8 bv = *(const short8*)((const char*)Vs + d * 256 + physv * 16);
        accO[fo] = __builtin_amdgcn_mfma_f32_16x16x32_bf16(ap, bv, accO[fo], 0, 0, 0);
      }
    }
    __syncthreads();
  }

  int b = bh >> 3, h = bh & 7;
#pragma unroll
  for (int fo = 0; fo < 4; ++fo) {
#pragma unroll
    for (int j = 0; j < 4; ++j) {
      int s = q0 + wid * 16 + (lane >> 4) * 4 + j;
      int d = fo * 16 + (lane & 15);
      float v = accO[fo][j] / l_r[j];
      X[(size_t)(b * S_ + s) * E_ + h * DH_ + d] = f2bf(v);
    }
  }
}

// ---------------- LayerNorm over E=512, 1 wave per row ----------------
__global__ __launch_bounds__(256) void ln_kernel(const float* __restrict__ Y,
                                                 const float* __restrict__ g,
                                                 const float* __restrict__ bta,
                                                 float* __restrict__ out) {
  int tid = threadIdx.x, lane = tid & 63, wid = tid >> 6;
  int row = blockIdx.x * 4 + wid;
  const float* y = Y + (size_t)row * E_;
  float4 v0 = *(const float4*)(y + lane * 8);
  float4 v1 = *(const float4*)(y + lane * 8 + 4);
  float s = v0.x + v0.y + v0.z + v0.w + v1.x + v1.y + v1.z + v1.w;
  float q = v0.x * v0.x + v0.y * v0.y + v0.z * v0.z + v0.w * v0.w +
            v1.x * v1.x + v1.y * v1.y + v1.z * v1.z + v1.w * v1.w;
#pragma unroll
  for (int msk = 1; msk < 64; msk <<= 1) {
    s += __shfl_xor(s, msk);
    q += __shfl_xor(q, msk);
  }
  float mu = s * (1.f / E_);
  float var = q * (1.f / E_) - mu * mu;
  float inv = rsqrtf(var + 1e-5f);
  float4 g0 = *(const float4*)(g + lane * 8);
  float4 g1 = *(const float4*)(g + lane * 8 + 4);
  float4 b0 = *(const float4*)(bta + lane * 8);
  float4 b1 = *(const float4*)(bta + lane * 8 + 4);
  float4 o0, o1;
  o0.x = (v0.x - mu) * inv * g0.x + b0.x;
  o0.y = (v0.y - mu) * inv * g0.y + b0.y;
  o0.z = (v0.z - mu) * inv * g0.z + b0.z;
  o0.w = (v0.w - mu) * inv * g0.w + b0.w;
  o1.x = (v1.x - mu) * inv * g1.x + b1.x;
  o1.y = (v1.y - mu) * inv * g1.y + b1.y;
  o1.z = (v1.z - mu) * inv * g1.z + b1.z;
  o1.w = (v1.w - mu) * inv * g1.w + b1.w;
  float* op = out + (size_t)row * E_;
  *(float4*)(op + lane * 8) = o0;
  *(float4*)(op + lane * 8 + 4) = o1;
}

extern "C" void kernel_launch(void* const* d_in, const int* in_sizes, int n_in,
                              void* d_out, int out_size, void* d_ws, size_t ws_size,
                              hipStream_t stream) {
  const float* q = (const float*)d_in[0];
  const float* k = (const float*)d_in[1];
  const float* v = (const float*)d_in[2];
  const float* Wq = (const float*)d_in[3];
  const float* bq = (const float*)d_in[4];
  const float* Wk = (const float*)d_in[5];
  const float* bk = (const float*)d_in[6];
  const float* Wv = (const float*)d_in[7];
  const float* bv = (const float*)d_in[8];
  const float* Wo = (const float*)d_in[9];
  const float* bo = (const float*)d_in[10];
  const float* ln_g = (const float*)d_in[11];
  const float* ln_b = (const float*)d_in[12];

  char* ws = (char*)d_ws;
  const size_t MB = 1024 * 1024;
  ushort* qb  = (ushort*)(ws + 0 * MB);
  ushort* kb  = (ushort*)(ws + 4 * MB);
  ushort* vb  = (ushort*)(ws + 8 * MB);
  ushort* Wqb = (ushort*)(ws + 12 * MB);
  ushort* Wkb = (ushort*)(ws + 12 * MB + 512 * 1024);
  ushort* Wvb = (ushort*)(ws + 13 * MB);
  ushort* Wob = (ushort*)(ws + 13 * MB + 512 * 1024);
  ushort* Qhb = (ushort*)(ws + 14 * MB);
  ushort* Khb = (ushort*)(ws + 18 * MB);
  ushort* Vhb = (ushort*)(ws + 22 * MB);
  ushort* Vtb = (ushort*)(ws + 26 * MB);
  ushort* Xb  = (ushort*)(ws + 30 * MB);
  float*  Yb  = (float*)(ws + 34 * MB);

  CvtArgs ca;
  ca.s[0] = q;  ca.d[0] = qb;  ca.nq[0] = (B_ * S_ * E_) / 4;
  ca.s[1] = k;  ca.d[1] = kb;  ca.nq[1] = (B_ * S_ * E_) / 4;
  ca.s[2] = v;  ca.d[2] = vb;  ca.nq[2] = (B_ * S_ * E_) / 4;
  ca.s[3] = Wq; ca.d[3] = Wqb; ca.nq[3] = (E_ * E_) / 4;
  ca.s[4] = Wk; ca.d[4] = Wkb; ca.nq[4] = (E_ * E_) / 4;
  ca.s[5] = Wv; ca.d[5] = Wvb; ca.nq[5] = (E_ * E_) / 4;
  ca.s[6] = Wo; ca.d[6] = Wob; ca.nq[6] = (E_ * E_) / 4;

  cvt_kernel<<<dim3(2048, 7), dim3(256), 0, stream>>>(ca);

  gemm_bt<0><<<dim3(4, 32, 3), dim3(256), 0, stream>>>(
      qb, kb, vb, Wqb, Wkb, Wvb, bq, bk, bv, Qhb, Khb, Vhb, (float*)nullptr);

  vtrans<<<dim3(S_ / 64, BH_), dim3(256), 0, stream>>>(Vhb, Vtb);

  attn_kernel<<<dim3(S_ / 64, BH_), dim3(256), 0, stream>>>(Qhb, Khb, Vtb, Xb);

  gemm_bt<1><<<dim3(4, 32, 1), dim3(256), 0, stream>>>(
      Xb, Xb, Xb, Wob, Wob, Wob, bo, bo, bo,
      (ushort*)nullptr, (ushort*)nullptr, (ushort*)nullptr, Yb);

  ln_kernel<<<dim3(M_ / 4), dim3(256), 0, stream>>>(Yb, ln_g, ln_b, (float*)d_out);
}

// Round 3
// 77.535 us; speedup vs baseline: 1.3846x; 1.3846x over previous
//
#include <hip/hip_runtime.h>
#include <hip/hip_bf16.h>
#include <stdint.h>

#define B_ 2
#define S_ 2048
#define E_ 512
#define H_ 8
#define DH_ 64
#define BH_ (B_*H_)
#define M_ (B_*S_)  // 4096

typedef short short8 __attribute__((ext_vector_type(8)));
typedef float f32x4 __attribute__((ext_vector_type(4)));
typedef float f32x16 __attribute__((ext_vector_type(16)));
typedef int int4v __attribute__((ext_vector_type(4)));

// 0.125 * log2(e): folded into Q projection so softmax uses native exp2
#define QSCALE 0.18033688011112042f

#if __has_builtin(__builtin_amdgcn_exp2f)
#define EXP2(x) __builtin_amdgcn_exp2f(x)
#else
#define EXP2(x) exp2f(x)
#endif

__device__ __forceinline__ float asf(uint32_t u) { return __builtin_bit_cast(float, u); }
__device__ __forceinline__ uint32_t asu(float f) { return __builtin_bit_cast(uint32_t, f); }

__device__ __forceinline__ ushort f2bf(float f) {
  uint32_t u = __builtin_bit_cast(uint32_t, f);
  u += 0x7fffu + ((u >> 16) & 1u);
  return (ushort)(u >> 16);
}

__device__ __forceinline__ uint32_t cvtpk(float lo, float hi) {
  uint32_t r;
  asm("v_cvt_pk_bf16_f32 %0, %1, %2" : "=v"(r) : "v"(lo), "v"(hi));
  return r;
}

// halves interleave: o0 = {lanes<32: a, lanes>=32: b from (lane-32)}
//                    o1 = {lanes<32: a from (lane+32), lanes>=32: b}
__device__ __forceinline__ void swap32(uint32_t a, uint32_t b, uint32_t& o0, uint32_t& o1) {
#if __has_builtin(__builtin_amdgcn_permlane32_swap)
  typedef int v2i __attribute__((ext_vector_type(2)));
  v2i r = __builtin_amdgcn_permlane32_swap((int)a, (int)b, false, false);
  o0 = (uint32_t)r.x; o1 = (uint32_t)r.y;
#else
  int laneid = (int)(threadIdx.x & 63);
  uint32_t pa = (uint32_t)__shfl_xor((int)a, 32, 64);
  uint32_t pb = (uint32_t)__shfl_xor((int)b, 32, 64);
  bool hi = laneid >= 32;
  o0 = hi ? pb : a;
  o1 = hi ? b : pa;
#endif
}

__device__ __forceinline__ void gll16(const void* g, void* l) {
  __builtin_amdgcn_global_load_lds((const __attribute__((address_space(1))) void*)g,
                                   (__attribute__((address_space(3))) void*)l,
                                   16, 0, 0);
}

// ---------------- fp32 -> bf16 conversion ----------------
struct CvtArgs {
  const float* s[7];
  ushort* d[7];
  int nq[7];
};

__global__ __launch_bounds__(256) void cvt_kernel(CvtArgs a) {
  int seg = blockIdx.y;
  int i = blockIdx.x * 256 + threadIdx.x;
  if (i >= a.nq[seg]) return;
  float4 v = ((const float4*)a.s[seg])[i];
  ushort4 o;
  o.x = f2bf(v.x); o.y = f2bf(v.y); o.z = f2bf(v.z); o.w = f2bf(v.w);
  ((ushort4*)a.d[seg])[i] = o;
}

// ---------------- bf16 GEMM: out = A @ W^T + bias ----------------
template<int EPI>
__global__ __launch_bounds__(256) void gemm_bt(
    const ushort* __restrict__ A0, const ushort* __restrict__ A1, const ushort* __restrict__ A2,
    const ushort* __restrict__ W0, const ushort* __restrict__ W1, const ushort* __restrict__ W2,
    const float* __restrict__ bias0, const float* __restrict__ bias1, const float* __restrict__ bias2,
    ushort* O0, ushort* O1, ushort* O2, float* Yout)
{
  const int K = E_;
  int z = blockIdx.z;
  const ushort* A = (z == 0) ? A0 : ((z == 1) ? A1 : A2);
  const ushort* W = (z == 0) ? W0 : ((z == 1) ? W1 : W2);
  const float* bias = (z == 0) ? bias0 : ((z == 1) ? bias1 : bias2);
  ushort* O = (z == 0) ? O0 : ((z == 1) ? O1 : O2);
  float scale = (EPI == 0 && z == 0) ? QSCALE : 1.0f;

  int n0 = blockIdx.x * 128, m0 = blockIdx.y * 128;
  int tid = threadIdx.x, lane = tid & 63, wid = tid >> 6;
  int wm = wid >> 1, wn = wid & 1;

  __shared__ ushort As[128 * 32];
  __shared__ ushort Bs[128 * 32];

  f32x4 acc[4][4];
#pragma unroll
  for (int i = 0; i < 4; ++i)
#pragma unroll
    for (int j = 0; j < 4; ++j)
      acc[i][j] = (f32x4){0.f, 0.f, 0.f, 0.f};

  for (int kt = 0; kt < K / 32; ++kt) {
    int k0 = kt * 32;
#pragma unroll
    for (int c = 0; c < 2; ++c) {
      int f = c * 256 + tid;
      int r = f >> 2;
      int lc = (f & 3) ^ ((r >> 1) & 3);
      gll16(A + (m0 + r) * K + k0 + lc * 8, (char*)As + (c * 256 + wid * 64) * 16);
    }
#pragma unroll
    for (int c = 0; c < 2; ++c) {
      int f = c * 256 + tid;
      int r = f >> 2;
      int lc = (f & 3) ^ ((r >> 1) & 3);
      gll16(W + (n0 + r) * K + k0 + lc * 8, (char*)Bs + (c * 256 + wid * 64) * 16);
    }
    __syncthreads();

    short8 af[4], bf[4];
#pragma unroll
    for (int fm = 0; fm < 4; ++fm) {
      int r = wm * 64 + fm * 16 + (lane & 15);
      int phys = (lane >> 4) ^ ((r >> 1) & 3);
      af[fm] = *(const short8*)((const char*)As + r * 64 + phys * 16);
    }
#pragma unroll
    for (int fn = 0; fn < 4; ++fn) {
      int r = wn * 64 + fn * 16 + (lane & 15);
      int phys = (lane >> 4) ^ ((r >> 1) & 3);
      bf[fn] = *(const short8*)((const char*)Bs + r * 64 + phys * 16);
    }
#pragma unroll
    for (int fm = 0; fm < 4; ++fm)
#pragma unroll
      for (int fn = 0; fn < 4; ++fn)
        acc[fm][fn] = __builtin_amdgcn_mfma_f32_16x16x32_bf16(af[fm], bf[fn], acc[fm][fn], 0, 0, 0);
    __syncthreads();
  }

#pragma unroll
  for (int fm = 0; fm < 4; ++fm) {
#pragma unroll
    for (int fn = 0; fn < 4; ++fn) {
#pragma unroll
      for (int j = 0; j < 4; ++j) {
        int m = m0 + wm * 64 + fm * 16 + (lane >> 4) * 4 + j;
        int n = n0 + wn * 64 + fn * 16 + (lane & 15);
        float v = (acc[fm][fn][j] + bias[n]) * scale;
        if constexpr (EPI == 0) {
          int b = m >> 11, s = m & (S_ - 1);
          int h = n >> 6, d = n & 63;
          O[((b * H_ + h) * S_ + s) * DH_ + d] = f2bf(v);
        } else {
          Yout[m * E_ + n] = v;
        }
      }
    }
  }
}

// ---------------- V transpose: [BH][S][DH] -> [BH][DH][S] ----------------
__global__ __launch_bounds__(256) void vtrans(const ushort* __restrict__ Vh, ushort* __restrict__ Vt) {
  int bh = blockIdx.y;
  int s0 = blockIdx.x * 64;
  __shared__ ushort t[64][72];
  int tid = threadIdx.x;
  const ushort* src = Vh + ((size_t)bh * S_ + s0) * DH_;
  int r = tid >> 2, c0 = (tid & 3) * 16;
#pragma unroll
  for (int i = 0; i < 2; ++i) {
    short8 v = *(const short8*)(src + r * DH_ + c0 + i * 8);
#pragma unroll
    for (int kx = 0; kx < 8; ++kx) t[r][c0 + i * 8 + kx] = (ushort)v[kx];
  }
  __syncthreads();
  int d = tid >> 2, j0 = (tid & 3) * 16;
  ushort* dst = Vt + ((size_t)bh * DH_ + d) * S_ + s0 + j0;
#pragma unroll
  for (int i = 0; i < 2; ++i) {
    short8 o;
#pragma unroll
    for (int kx = 0; kx < 8; ++kx) o[kx] = (short)t[j0 + i * 8 + kx][d];
    *(short8*)(dst + i * 8) = o;
  }
}

// ---------------- flash attention, swapped-operand 32x32 structure ----------------
// Q [BH][S][64] bf16 (pre-scaled by 0.125*log2e), K [BH][S][64] bf16, Vt [BH][64][S] bf16.
// Block: 256 thr = 4 waves = 2 q-subtiles x 2 KV-halves. QBLK=64, KVBLK=64 per step.
// Swapped QK^T (S^T[k][q]) and swapped PV (O^T[d][q]): softmax fully lane-local,
// P rebuilt in-register via cvt_pk + permlane32_swap (T12). KV double-buffered LDS.
__global__ __launch_bounds__(256, 2) void attn_kernel(const ushort* __restrict__ Qh,
                                                      const ushort* __restrict__ Kh,
                                                      const ushort* __restrict__ Vt,
                                                      ushort* __restrict__ X) {
  int bh = blockIdx.x;
  int q0 = blockIdx.y * 64;
  int tid = threadIdx.x, lane = tid & 63, wid = tid >> 6;
  int wq = wid & 1, wk = wid >> 1;
  int hi = lane >> 5;

  // [2 buf][2 wk][ K tile 64x64 | V tile 64x64 ] = 64 KiB
  __shared__ ushort lds_[32768];
  char* L = (char*)lds_;

  const ushort* Kg = Kh + (size_t)bh * S_ * DH_;
  const ushort* Vg = Vt + (size_t)bh * DH_ * S_;

  // Q fragments in registers: B-operand of swapped QK^T.
  int q = q0 + wq * 32 + (lane & 31);
  const ushort* Qrow = Qh + ((size_t)bh * S_ + q) * DH_;
  short8 qf[4];
#pragma unroll
  for (int ds = 0; ds < 4; ++ds)
    qf[ds] = *(const short8*)(Qrow + ds * 16 + hi * 8);

  f32x16 sacc[2], oacc[2];
#pragma unroll
  for (int r = 0; r < 16; ++r) { oacc[0][r] = 0.f; oacc[1][r] = 0.f; }
  float m_r = -INFINITY, l_r = 0.f;

  const int NT = 16;  // steps; wave wk handles kv tiles [wk*1024 + t*64)

#define STAGE(buf, t)                                                          \
  do {                                                                         \
    int kb0 = (t) * 64, kb1 = 1024 + (t) * 64;                                 \
    _Pragma("unroll")                                                          \
    for (int w2 = 0; w2 < 2; ++w2) {                                           \
      int kb = w2 ? kb1 : kb0;                                                 \
      char* Kd = L + (buf) * 32768 + w2 * 16384;                               \
      char* Vd = Kd + 8192;                                                    \
      _Pragma("unroll")                                                        \
      for (int c = 0; c < 2; ++c) {                                            \
        int f = c * 256 + tid;                                                 \
        int r = f >> 3;                                                        \
        int lc = (f & 7) ^ (r & 7);                                            \
        gll16(Kg + (size_t)(kb + r) * DH_ + lc * 8, Kd + (c * 256 + wid * 64) * 16); \
        gll16(Vg + (size_t)r * S_ + kb + lc * 8, Vd + (c * 256 + wid * 64) * 16);    \
      }                                                                        \
    }                                                                          \
  } while (0)

  STAGE(0, 0);
  __syncthreads();

  for (int t = 0; t < NT; ++t) {
    int cur = t & 1;
    if (t + 1 < NT) STAGE(cur ^ 1, t + 1);

    const char* Kt = L + cur * 32768 + wk * 16384;
    const char* Vtile = Kt + 8192;

    // ---- QK^T (swapped): sacc[c] = S^T[k= c*32+..][q] ----
#pragma unroll
    for (int c = 0; c < 2; ++c) {
#pragma unroll
      for (int r = 0; r < 16; ++r) sacc[c][r] = 0.f;
      int kl = c * 32 + (lane & 31);
#pragma unroll
      for (int ds = 0; ds < 4; ++ds) {
        short8 kf = *(const short8*)(Kt + kl * 128 + (((2 * ds + hi) ^ (kl & 7)) * 16));
        sacc[c] = __builtin_amdgcn_mfma_f32_32x32x16_bf16(kf, qf[ds], sacc[c], 0, 0, 0);
      }
    }

    // ---- online softmax (lane-local over k, 1 permlane exchange) ----
    float mx = sacc[0][0];
#pragma unroll
    for (int r = 1; r < 16; ++r) mx = fmaxf(mx, sacc[0][r]);
#pragma unroll
    for (int r = 0; r < 16; ++r) mx = fmaxf(mx, sacc[1][r]);
    {
      uint32_t e0, e1;
      swap32(asu(mx), asu(mx), e0, e1);
      mx = fmaxf(asf(e0), asf(e1));
    }
    float mnew = fmaxf(m_r, mx);
    float scf = EXP2(m_r - mnew);
    m_r = mnew;
    float rs = 0.f;
#pragma unroll
    for (int c = 0; c < 2; ++c)
#pragma unroll
      for (int r = 0; r < 16; ++r) {
        float p = EXP2(sacc[c][r] - mnew);
        sacc[c][r] = p;
        rs += p;
      }
    {
      uint32_t e0, e1;
      swap32(asu(rs), asu(rs), e0, e1);
      rs = asf(e0) + asf(e1);
    }
    l_r = l_r * scf + rs;
#pragma unroll
    for (int dblk = 0; dblk < 2; ++dblk)
#pragma unroll
      for (int r = 0; r < 16; ++r) oacc[dblk][r] *= scf;

    // ---- pack P to bf16 words; rebuild PV B-frags via half-swaps (T12) ----
    uint32_t w[2][8];
#pragma unroll
    for (int c = 0; c < 2; ++c)
#pragma unroll
      for (int i = 0; i < 8; ++i)
        w[c][i] = cvtpk(sacc[c][2 * i], sacc[c][2 * i + 1]);

    short8 pf[4];
#pragma unroll
    for (int ks = 0; ks < 4; ++ks) {
      int c = ks >> 1, j = ks & 1;
      uint32_t e01, e45, e23, e67;
      swap32(w[c][4 * j + 0], w[c][4 * j + 2], e01, e45);
      swap32(w[c][4 * j + 1], w[c][4 * j + 3], e23, e67);
      int4v iv;
      iv[0] = (int)e01; iv[1] = (int)e23; iv[2] = (int)e45; iv[3] = (int)e67;
      pf[ks] = __builtin_bit_cast(short8, iv);
    }

    // ---- PV (swapped): oacc[dblk] += V^T x P  -> O^T[d][q] ----
#pragma unroll
    for (int ks = 0; ks < 4; ++ks) {
      int dl0 = (lane & 31);
#pragma unroll
      for (int dblk = 0; dblk < 2; ++dblk) {
        int dl = dblk * 32 + dl0;
        short8 vf = *(const short8*)(Vtile + dl * 128 + (((2 * ks + hi) ^ (dl & 7)) * 16));
        oacc[dblk] = __builtin_amdgcn_mfma_f32_32x32x16_bf16(vf, pf[ks], oacc[dblk], 0, 0, 0);
      }
    }

    __syncthreads();
  }
#undef STAGE

  // ---- merge the two KV-half waves (elementwise: same lane<->same (q,d,reg)) ----
  // scratch layout in fl: O partials [0,4096), m [4096,4224), l [4224,4352)
  float* fl = (float*)L;
  if (wk == 1) {
#pragma unroll
    for (int dblk = 0; dblk < 2; ++dblk)
#pragma unroll
      for (int r = 0; r < 16; ++r)
        fl[((wq * 2 + dblk) * 16 + r) * 64 + lane] = oacc[dblk][r];
    fl[4096 + wq * 64 + lane] = m_r;
    fl[4224 + wq * 64 + lane] = l_r;
  }
  __syncthreads();
  if (wk == 0) {
    float m1 = fl[4096 + wq * 64 + lane];
    float l1 = fl[4224 + wq * 64 + lane];
    float mstar = fmaxf(m_r, m1);
    float a0 = EXP2(m_r - mstar);
    float a1 = EXP2(m1 - mstar);
    float lstar = l_r * a0 + l1 * a1;
    float invl = 1.0f / lstar;
    int b = bh >> 3, h = bh & 7;
    int s = q0 + wq * 32 + (lane & 31);
    ushort* Xrow = X + (size_t)(b * S_ + s) * E_ + h * DH_;
#pragma unroll
    for (int dblk = 0; dblk < 2; ++dblk) {
#pragma unroll
      for (int i = 0; i < 8; ++i) {
        int r0 = 2 * i, r1 = 2 * i + 1;
        float o0 = (oacc[dblk][r0] * a0 + fl[((wq * 2 + dblk) * 16 + r0) * 64 + lane] * a1) * invl;
        float o1 = (oacc[dblk][r1] * a0 + fl[((wq * 2 + dblk) * 16 + r1) * 64 + lane] * a1) * invl;
        int d = dblk * 32 + (r0 & 3) + 8 * (r0 >> 2) + 4 * hi;
        *(uint32_t*)(Xrow + d) = cvtpk(o0, o1);
      }
    }
  }
}

// ---------------- LayerNorm over E=512, 1 wave per row ----------------
__global__ __launch_bounds__(256) void ln_kernel(const float* __restrict__ Y,
                                                 const float* __restrict__ g,
                                                 const float* __restrict__ bta,
                                                 float* __restrict__ out) {
  int tid = threadIdx.x, lane = tid & 63, wid = tid >> 6;
  int row = blockIdx.x * 4 + wid;
  const float* y = Y + (size_t)row * E_;
  float4 v0 = *(const float4*)(y + lane * 8);
  float4 v1 = *(const float4*)(y + lane * 8 + 4);
  float s = v0.x + v0.y + v0.z + v0.w + v1.x + v1.y + v1.z + v1.w;
  float q = v0.x * v0.x + v0.y * v0.y + v0.z * v0.z + v0.w * v0.w +
            v1.x * v1.x + v1.y * v1.y + v1.z * v1.z + v1.w * v1.w;
#pragma unroll
  for (int msk = 1; msk < 64; msk <<= 1) {
    s += __shfl_xor(s, msk);
    q += __shfl_xor(q, msk);
  }
  float mu = s * (1.f / E_);
  float var = q * (1.f / E_) - mu * mu;
  float inv = rsqrtf(var + 1e-5f);
  float4 g0 = *(const float4*)(g + lane * 8);
  float4 g1 = *(const float4*)(g + lane * 8 + 4);
  float4 b0 = *(const float4*)(bta + lane * 8);
  float4 b1 = *(const float4*)(bta + lane * 8 + 4);
  float4 o0, o1;
  o0.x = (v0.x - mu) * inv * g0.x + b0.x;
  o0.y = (v0.y - mu) * inv * g0.y + b0.y;
  o0.z = (v0.z - mu) * inv * g0.z + b0.z;
  o0.w = (v0.w - mu) * inv * g0.w + b0.w;
  o1.x = (v1.x - mu) * inv * g1.x + b1.x;
  o1.y = (v1.y - mu) * inv * g1.y + b1.y;
  o1.z = (v1.z - mu) * inv * g1.z + b1.z;
  o1.w = (v1.w - mu) * inv * g1.w + b1.w;
  float* op = out + (size_t)row * E_;
  *(float4*)(op + lane * 8) = o0;
  *(float4*)(op + lane * 8 + 4) = o1;
}

extern "C" void kernel_launch(void* const* d_in, const int* in_sizes, int n_in,
                              void* d_out, int out_size, void* d_ws, size_t ws_size,
                              hipStream_t stream) {
  const float* q = (const float*)d_in[0];
  const float* k = (const float*)d_in[1];
  const float* v = (const float*)d_in[2];
  const float* Wq = (const float*)d_in[3];
  const float* bq = (const float*)d_in[4];
  const float* Wk = (const float*)d_in[5];
  const float* bk = (const float*)d_in[6];
  const float* Wv = (const float*)d_in[7];
  const float* bv = (const float*)d_in[8];
  const float* Wo = (const float*)d_in[9];
  const float* bo = (const float*)d_in[10];
  const float* ln_g = (const float*)d_in[11];
  const float* ln_b = (const float*)d_in[12];

  char* ws = (char*)d_ws;
  const size_t MB = 1024 * 1024;
  ushort* qb  = (ushort*)(ws + 0 * MB);
  ushort* kb  = (ushort*)(ws + 4 * MB);
  ushort* vb  = (ushort*)(ws + 8 * MB);
  ushort* Wqb = (ushort*)(ws + 12 * MB);
  ushort* Wkb = (ushort*)(ws + 12 * MB + 512 * 1024);
  ushort* Wvb = (ushort*)(ws + 13 * MB);
  ushort* Wob = (ushort*)(ws + 13 * MB + 512 * 1024);
  ushort* Qhb = (ushort*)(ws + 14 * MB);
  ushort* Khb = (ushort*)(ws + 18 * MB);
  ushort* Vhb = (ushort*)(ws + 22 * MB);
  ushort* Vtb = (ushort*)(ws + 26 * MB);
  ushort* Xb  = (ushort*)(ws + 30 * MB);
  float*  Yb  = (float*)(ws + 34 * MB);

  CvtArgs ca;
  ca.s[0] = q;  ca.d[0] = qb;  ca.nq[0] = (B_ * S_ * E_) / 4;
  ca.s[1] = k;  ca.d[1] = kb;  ca.nq[1] = (B_ * S_ * E_) / 4;
  ca.s[2] = v;  ca.d[2] = vb;  ca.nq[2] = (B_ * S_ * E_) / 4;
  ca.s[3] = Wq; ca.d[3] = Wqb; ca.nq[3] = (E_ * E_) / 4;
  ca.s[4] = Wk; ca.d[4] = Wkb; ca.nq[4] = (E_ * E_) / 4;
  ca.s[5] = Wv; ca.d[5] = Wvb; ca.nq[5] = (E_ * E_) / 4;
  ca.s[6] = Wo; ca.d[6] = Wob; ca.nq[6] = (E_ * E_) / 4;

  cvt_kernel<<<dim3(2048, 7), dim3(256), 0, stream>>>(ca);

  gemm_bt<0><<<dim3(4, 32, 3), dim3(256), 0, stream>>>(
      qb, kb, vb, Wqb, Wkb, Wvb, bq, bk, bv, Qhb, Khb, Vhb, (float*)nullptr);

  vtrans<<<dim3(S_ / 64, BH_), dim3(256), 0, stream>>>(Vhb, Vtb);

  attn_kernel<<<dim3(BH_, S_ / 64), dim3(256), 0, stream>>>(Qhb, Khb, Vtb, Xb);

  gemm_bt<1><<<dim3(4, 32, 1), dim3(256), 0, stream>>>(
      Xb, Xb, Xb, Wob, Wob, Wob, bo, bo, bo,
      (ushort*)nullptr, (ushort*)nullptr, (ushort*)nullptr, Yb);

  ln_kernel<<<dim3(M_ / 4), dim3(256), 0, stream>>>(Yb, ln_g, ln_b, (float*)d_out);
}